// Round 1
// baseline (171.709 us; speedup 1.0000x reference)
//
#include <hip/hip_runtime.h>
#include <math.h>

#define MESH 4194304

// deformed[0] = state[0]; deformed[i] = R(theta[i-1]) @ state[i] for i >= 1
__device__ __forceinline__ float2 deformed_at(const float* __restrict__ theta,
                                              const float2* __restrict__ state, int i) {
  float2 st = state[i];
  if (i == 0) return st;
  float t = theta[i - 1];
  float s, c;
  __sincosf(t, &s, &c);
  return make_float2(c * st.x - s * st.y, s * st.x + c * st.y);
}

__global__ void init_acc_kernel(double* __restrict__ acc) {
  if (threadIdx.x < 4) acc[threadIdx.x] = 0.0;
}

// Pass 1: loss_v = sum vols, loss_s = sum vols^2
__global__ void pass1_kernel(const float* __restrict__ theta,
                             const float2* __restrict__ state,
                             double* __restrict__ acc) {
  float lv = 0.f, ls = 0.f;
  const int stride = gridDim.x * blockDim.x;
  for (int i = blockIdx.x * blockDim.x + threadIdx.x; i < MESH; i += stride) {
    float2 a = deformed_at(theta, state, i);
    const int ip1 = (i + 1 == MESH) ? 0 : i + 1;
    float2 b = deformed_at(theta, state, ip1);
    const float dot = a.x * b.x + a.y * b.y;
    const float v2 = fabsf(1.f - dot * dot);   // vols^2
    lv += sqrtf(v2);
    ls += v2;
  }
  // wave-64 shuffle reduce, then LDS across the 4 waves of the block
  for (int off = 32; off > 0; off >>= 1) {
    lv += __shfl_down(lv, off, 64);
    ls += __shfl_down(ls, off, 64);
  }
  __shared__ float s1[4], s2[4];
  const int lane = threadIdx.x & 63, wid = threadIdx.x >> 6;
  if (lane == 0) { s1[wid] = lv; s2[wid] = ls; }
  __syncthreads();
  if (threadIdx.x == 0) {
    atomicAdd(&acc[0], (double)(s1[0] + s1[1] + s1[2] + s1[3]));
    atomicAdd(&acc[1], (double)(s2[0] + s2[1] + s2[2] + s2[3]));
  }
}

// Pass 2: loss_so2, needs avg_len = acc[0]/M from pass 1
__global__ void pass2_kernel(const float* __restrict__ theta,
                             const float2* __restrict__ state,
                             double* __restrict__ acc) {
  const float avg_len = (float)(fabs(acc[0]) * (1.0 / (double)MESH));
  const float inv_avg = 1.0f / avg_len;
  float lso = 0.f;
  const int stride = gridDim.x * blockDim.x;
  for (int j = blockIdx.x * blockDim.x + threadIdx.x; j < MESH; j += stride) {
    float2 a = deformed_at(theta, state, j);
    const int jp1 = (j + 1 == MESH) ? 0 : j + 1;
    float2 b = deformed_at(theta, state, jp1);
    const float dot = a.x * b.x + a.y * b.y;
    const float e = 1.f - dot * dot;
    float term;
    if (j == MESH - 1) {
      // sim_last: exp(-(1-dot^2)/avg_len)  -- no sqrt, no abs (per reference)
      term = fabsf(theta[MESH - 2]) * __expf(-e * inv_avg);
    } else {
      const float v = sqrtf(fabsf(e));  // vols[j]
      const float w = (j == 0) ? fabsf(theta[0]) : fabsf(theta[j - 1] - theta[j]);
      term = w * __expf(-v * inv_avg);
    }
    lso += term;
  }
  for (int off = 32; off > 0; off >>= 1) lso += __shfl_down(lso, off, 64);
  __shared__ float s1[4];
  const int lane = threadIdx.x & 63, wid = threadIdx.x >> 6;
  if (lane == 0) s1[wid] = lso;
  __syncthreads();
  if (threadIdx.x == 0) {
    atomicAdd(&acc[2], (double)(s1[0] + s1[1] + s1[2] + s1[3]));
  }
}

__global__ void finalize_kernel(const double* __restrict__ acc, float* __restrict__ out) {
  out[0] = (float)(acc[0] + acc[1] + acc[2]);
}

extern "C" void kernel_launch(void* const* d_in, const int* in_sizes, int n_in,
                              void* d_out, int out_size, void* d_ws, size_t ws_size,
                              hipStream_t stream) {
  const float* theta  = (const float*)d_in[0];   // (MESH-1,) f32
  const float2* state = (const float2*)d_in[1];  // (MESH, 2) f32
  double* acc = (double*)d_ws;                   // 4 doubles of scratch
  float* out  = (float*)d_out;

  init_acc_kernel<<<1, 64, 0, stream>>>(acc);
  const int threads = 256;
  const int blocks  = 2048;  // 8192 waves = full residency; grid-stride inside
  pass1_kernel<<<blocks, threads, 0, stream>>>(theta, state, acc);
  pass2_kernel<<<blocks, threads, 0, stream>>>(theta, state, acc);
  finalize_kernel<<<1, 1, 0, stream>>>(acc, out);
}